// Round 3
// baseline (1368.139 us; speedup 1.0000x reference)
//
#include <hip/hip_runtime.h>
#include <hip/hip_bf16.h>
#include <stdint.h>

#define HID 256
#define BOT 32

// ---------------------------------------------------------------------------
// ws layout:
//   [0)            int   flags[4]   (flags[0]: 0 = int32 edges, 1 = int64 edges)
//   [16)           int   deg[N]
//   [16+4N)        float dinv[N]
//   [16+8N)        float P[N*32]    (layer-1 proj; reused as A2 in layer 2)
//   [16+8N+128N)   float A1[N*32]   (layer-1 aggregate -> h1)
// total = 16 + 264*N  (~26.4 MB @ N=100000)
// ---------------------------------------------------------------------------

// Detect int64-vs-int32 edge_index: int64 values < 2^31 have all-zero high words
// (little-endian). For int32 edges the odd slots hold real node indices — the
// chance that 512 random indices in [0,100000) are ALL zero is ~0.
__global__ void k_detect(const int* __restrict__ ei, int* __restrict__ flags) {
    int t = threadIdx.x;           // 64 threads
    int found = 0;
    for (int i = 0; i < 8; ++i) {
        int slot = 2 * (t * 8 + i) + 1;   // odd slots 1..1023 — in-range for both widths
        if (ei[slot] != 0) found = 1;
    }
    unsigned long long b = __ballot(found);
    if (t == 0) flags[0] = (b == 0ULL) ? 1 : 0;
}

__global__ void k_deg(const int* __restrict__ ei, int E, int* __restrict__ deg,
                      const int* __restrict__ flags) {
    int mode = flags[0];
    int e = blockIdx.x * blockDim.x + threadIdx.x;
    if (e >= E) return;
    int d = mode ? ei[2 * E + 2 * e] : ei[E + e];
    atomicAdd(deg + d, 1);
}

__global__ void k_dinv(const int* __restrict__ deg, float* __restrict__ dinv, int N) {
    int i = blockIdx.x * blockDim.x + threadIdx.x;
    if (i < N) dinv[i] = rsqrtf((float)(deg[i] + 1));  // +1 self-loop
}

// P[n,j] = sum_k x[n,k] * Wd[j,k] ; lanes j=0..31, 2 nodes per 32-lane group
__global__ __launch_bounds__(256) void k_gemm_down(
    const float* __restrict__ x, const float* __restrict__ Wd,
    float* __restrict__ P, int N)
{
    __shared__ float w[BOT][HID + 1];   // +1 pad; conflict-free scalar reads
    for (int i = threadIdx.x; i < BOT * HID; i += 256)
        w[i >> 8][i & 255] = Wd[i];
    __syncthreads();

    int t = blockIdx.x * 256 + threadIdx.x;
    int g = t >> 5, j = t & 31;
    int n0 = g * 2;
    if (n0 >= N) return;
    bool v1 = (n0 + 1) < N;

    const float4* xr0 = (const float4*)(x + (size_t)n0 * HID);
    const float4* xr1 = (const float4*)(x + (size_t)(v1 ? n0 + 1 : n0) * HID);

    float acc0 = 0.f, acc1 = 0.f;
    #pragma unroll 8
    for (int c = 0; c < HID / 4; ++c) {
        float4 a = xr0[c];
        float4 b = xr1[c];
        int k = c * 4;
        float w0 = w[j][k], w1 = w[j][k + 1], w2 = w[j][k + 2], w3 = w[j][k + 3];
        acc0 += a.x * w0 + a.y * w1 + a.z * w2 + a.w * w3;
        acc1 += b.x * w0 + b.y * w1 + b.z * w2 + b.w * w3;
    }
    P[(size_t)n0 * BOT + j] = acc0;
    if (v1) P[(size_t)(n0 + 1) * BOT + j] = acc1;
}

// dst[t] = dinv[node]^2 * src[t]   (self-loop term; also replaces zero-init)
__global__ void k_selfinit(const float* __restrict__ src, const float* __restrict__ dinv,
                           float* __restrict__ dst, int NB) {
    int t = blockIdx.x * blockDim.x + threadIdx.x;
    if (t < NB) {
        float di = dinv[t >> 5];
        dst[t] = di * di * src[t];
    }
}

// edge scatter: 8 threads per edge, float4 per thread, fp32 HW atomics
__global__ void k_scatter(const int* __restrict__ ei, int E,
                          const float* __restrict__ dinv,
                          const float* __restrict__ src_feat,
                          float* __restrict__ dst_acc,
                          const int* __restrict__ flags)
{
    int mode = flags[0];
    int t = blockIdx.x * blockDim.x + threadIdx.x;
    int e = t >> 3;
    if (e >= E) return;
    int q = t & 7;
    int s, d;
    if (mode) { s = ei[2 * e]; d = ei[2 * E + 2 * e]; }
    else      { s = ei[e];     d = ei[E + e]; }
    float nm = dinv[s] * dinv[d];
    float4 v = *(const float4*)(src_feat + (size_t)s * BOT + q * 4);
    float* o = dst_acc + (size_t)d * BOT + q * 4;
    unsafeAtomicAdd(o + 0, nm * v.x);
    unsafeAtomicAdd(o + 1, nm * v.y);
    unsafeAtomicAdd(o + 2, nm * v.z);
    unsafeAtomicAdd(o + 3, nm * v.w);
}

// h1 = relu(A1 + b_down), in place
__global__ void k_act(float* __restrict__ A1, const float* __restrict__ bdown, int NB) {
    int t = blockIdx.x * blockDim.x + threadIdx.x;
    if (t < NB) {
        float v = A1[t] + bdown[t & 31];
        A1[t] = v > 0.f ? v : 0.f;
    }
}

// out[n,k] = sum_j A2[n,j]*Wup[k,j] + b_up[k] + x[n,k]   (fp32 output)
__global__ __launch_bounds__(256) void k_out(
    const float* __restrict__ A2, const float* __restrict__ x,
    const float* __restrict__ Wup, const float* __restrict__ bup,
    float* __restrict__ out, int N, int npb)
{
    int k = threadIdx.x;
    float wreg[BOT];
    const float4* wr = (const float4*)(Wup + (size_t)k * BOT);
    #pragma unroll
    for (int c = 0; c < BOT / 4; ++c) {
        float4 v = wr[c];
        wreg[c * 4 + 0] = v.x; wreg[c * 4 + 1] = v.y;
        wreg[c * 4 + 2] = v.z; wreg[c * 4 + 3] = v.w;
    }
    float bk = bup[k];

    int n0 = blockIdx.x * npb;
    int n1 = n0 + npb;
    if (n1 > N) n1 = N;
    for (int n = n0; n < n1; ++n) {
        const float* av = A2 + (size_t)n * BOT;
        float s0 = 0.f, s1 = 0.f, s2 = 0.f, s3 = 0.f;
        #pragma unroll
        for (int j = 0; j < BOT; j += 4) {
            s0 += av[j + 0] * wreg[j + 0];
            s1 += av[j + 1] * wreg[j + 1];
            s2 += av[j + 2] * wreg[j + 2];
            s3 += av[j + 3] * wreg[j + 3];
        }
        float acc = bk + ((s0 + s1) + (s2 + s3));
        out[(size_t)n * HID + k] = acc + x[(size_t)n * HID + k];
    }
}

extern "C" void kernel_launch(void* const* d_in, const int* in_sizes, int n_in,
                              void* d_out, int out_size, void* d_ws, size_t ws_size,
                              hipStream_t stream) {
    const float* x  = (const float*)d_in[0];
    const int*   ei = (const int*)d_in[1];
    const float* Wd = (const float*)d_in[2];
    const float* bd = (const float*)d_in[3];
    const float* Wu = (const float*)d_in[4];
    const float* bu = (const float*)d_in[5];
    float* out = (float*)d_out;

    int N = in_sizes[0] / HID;   // 100000
    int E = in_sizes[1] / 2;     // 800000 (flat element count is 2E for both widths)
    int NB = N * BOT;

    char* ws = (char*)d_ws;
    int*   flags = (int*)ws;
    int*   deg   = (int*)(ws + 16);
    float* dinv  = (float*)(ws + 16 + (size_t)N * 4);
    float* P     = (float*)(ws + 16 + (size_t)N * 8);                     // N*32
    float* A1    = (float*)(ws + 16 + (size_t)N * 8 + (size_t)N * 128);   // N*32

    k_detect<<<1, 64, 0, stream>>>(ei, flags);
    hipMemsetAsync(deg, 0, (size_t)N * 4, stream);
    k_deg<<<(E + 255) / 256, 256, 0, stream>>>(ei, E, deg, flags);
    k_dinv<<<(N + 255) / 256, 256, 0, stream>>>(deg, dinv, N);

    // Layer 1: P = x @ Wd^T ; A1 = dinv^2*P + scatter(norm*P[src]) ; h1 = relu(A1+bd)
    k_gemm_down<<<(((N + 1) / 2) * 32 + 255) / 256, 256, 0, stream>>>(x, Wd, P, N);
    k_selfinit<<<(NB + 255) / 256, 256, 0, stream>>>(P, dinv, A1, NB);
    k_scatter<<<(E * 8 + 255) / 256, 256, 0, stream>>>(ei, E, dinv, P, A1, flags);
    k_act<<<(NB + 255) / 256, 256, 0, stream>>>(A1, bd, NB);

    // Layer 2: A2 = dinv^2*h1 + scatter(norm*h1[src])  (A2 reuses P buffer)
    k_selfinit<<<(NB + 255) / 256, 256, 0, stream>>>(A1, dinv, P, NB);
    k_scatter<<<(E * 8 + 255) / 256, 256, 0, stream>>>(ei, E, dinv, A1, P, flags);

    // out = A2 @ Wu^T + bu + x
    int npb = (N + 2499) / 2500;
    k_out<<<(N + npb - 1) / npb, 256, 0, stream>>>(P, x, Wu, bu, out, N, npb);
}

// Round 4
// 516.682 us; speedup vs baseline: 2.6479x; 2.6479x over previous
//
#include <hip/hip_runtime.h>
#include <hip/hip_bf16.h>
#include <stdint.h>

#define HID 256
#define BOT 32

// ---------------------------------------------------------------------------
// ws layout (N=100000, E=800000 -> ~33.6 MB):
//   [0)              int   flags[4]  (flags[0]: edge width mode; flags[1]: CSR cursor)
//   [16)             int   deg[N]
//   [16+4N)          float dinv[N]
//   [16+8N)          int   start[N]   (CSR region start per node)
//   [16+12N)         int   cur[N]     (fill cursor; == region end after k_fill)
//   [16+16N)         int2  srcw[E]    (src index, norm weight bits)
//   [16+16N+8E)      float P[N*32]    (layer-1 proj; reused as A2)
//   [16+16N+8E+128N) float A1[N*32]   (layer-1 aggregate -> h1)
// ---------------------------------------------------------------------------

// Detect int64-vs-int32 edge_index: int64 values < 2^31 have all-zero high words.
__global__ void k_detect(const int* __restrict__ ei, int* __restrict__ flags) {
    int t = threadIdx.x;           // 64 threads
    int found = 0;
    for (int i = 0; i < 8; ++i) {
        int slot = 2 * (t * 8 + i) + 1;   // odd slots — in-range for both widths
        if (ei[slot] != 0) found = 1;
    }
    unsigned long long b = __ballot(found);
    if (t == 0) flags[0] = (b == 0ULL) ? 1 : 0;
}

__global__ void k_deg(const int* __restrict__ ei, int E, int* __restrict__ deg,
                      const int* __restrict__ flags) {
    int mode = flags[0];
    int e = blockIdx.x * blockDim.x + threadIdx.x;
    if (e >= E) return;
    int d = mode ? ei[2 * E + 2 * e] : ei[E + e];
    atomicAdd(deg + d, 1);
}

__global__ void k_dinv(const int* __restrict__ deg, float* __restrict__ dinv, int N) {
    int i = blockIdx.x * blockDim.x + threadIdx.x;
    if (i < N) dinv[i] = rsqrtf((float)(deg[i] + 1));  // +1 self-loop
}

// Per-node CSR region allocation: block-local scan + one global atomic per block.
// Regions are disjoint; cross-node ordering is irrelevant for gather.
__global__ __launch_bounds__(256) void k_alloc(const int* __restrict__ deg,
                                               int* __restrict__ start,
                                               int* __restrict__ cur,
                                               int* __restrict__ cursor, int N) {
    __shared__ int sdata[256];
    __shared__ int sbase;
    int tid = threadIdx.x;
    int i = blockIdx.x * 256 + tid;
    int d = (i < N) ? deg[i] : 0;
    sdata[tid] = d;
    __syncthreads();
    // Hillis-Steele inclusive scan
    for (int off = 1; off < 256; off <<= 1) {
        int t = (tid >= off) ? sdata[tid - off] : 0;
        __syncthreads();
        sdata[tid] += t;
        __syncthreads();
    }
    if (tid == 0) sbase = atomicAdd(cursor, sdata[255]);
    __syncthreads();
    if (i < N) {
        int st = sbase + sdata[tid] - d;   // exclusive offset within block
        start[i] = st;
        cur[i] = st;
    }
}

// Place each edge into its destination's CSR region, with precomputed norm.
__global__ void k_fill(const int* __restrict__ ei, int E,
                       const float* __restrict__ dinv,
                       int* __restrict__ cur, int2* __restrict__ srcw,
                       const int* __restrict__ flags) {
    int mode = flags[0];
    int e = blockIdx.x * blockDim.x + threadIdx.x;
    if (e >= E) return;
    int s, d;
    if (mode) { s = ei[2 * e]; d = ei[2 * E + 2 * e]; }
    else      { s = ei[e];     d = ei[E + e]; }
    float w = dinv[s] * dinv[d];
    int slot = atomicAdd(cur + d, 1);
    srcw[slot] = make_int2(s, __float_as_int(w));
}

// Gather-aggregate: 32 lanes per node, lane j owns feature j.
// dst[n,j] = dinv[n]^2 * feat[n,j] + sum_{e in CSR[n]} w_e * feat[src_e, j]
// relu_bias: dst = max(dst + bias[j], 0)
__global__ __launch_bounds__(256) void k_gather(
    const float* __restrict__ feat, const float* __restrict__ dinv,
    const int* __restrict__ start, const int* __restrict__ endp,
    const int2* __restrict__ srcw, const float* __restrict__ bias,
    float* __restrict__ dst, int N, int relu_bias)
{
    int t = blockIdx.x * 256 + threadIdx.x;
    int n = t >> 5, j = t & 31;
    if (n >= N) return;
    float di = dinv[n];
    float acc = di * di * feat[(size_t)n * BOT + j];
    int st = start[n], en = endp[n];
    for (int k = st; k < en; ++k) {
        int2 p = srcw[k];                       // same-address broadcast across 32 lanes
        acc += __int_as_float(p.y) * feat[(size_t)p.x * BOT + j];  // coalesced 128B
    }
    if (relu_bias) {
        acc += bias[j];
        acc = acc > 0.f ? acc : 0.f;
    }
    dst[(size_t)n * BOT + j] = acc;
}

// P[n,j] = sum_k x[n,k] * Wd[j,k] ; lanes j=0..31, 2 nodes per 32-lane group
__global__ __launch_bounds__(256) void k_gemm_down(
    const float* __restrict__ x, const float* __restrict__ Wd,
    float* __restrict__ P, int N)
{
    __shared__ float w[BOT][HID + 1];
    for (int i = threadIdx.x; i < BOT * HID; i += 256)
        w[i >> 8][i & 255] = Wd[i];
    __syncthreads();

    int t = blockIdx.x * 256 + threadIdx.x;
    int g = t >> 5, j = t & 31;
    int n0 = g * 2;
    if (n0 >= N) return;
    bool v1 = (n0 + 1) < N;

    const float4* xr0 = (const float4*)(x + (size_t)n0 * HID);
    const float4* xr1 = (const float4*)(x + (size_t)(v1 ? n0 + 1 : n0) * HID);

    float acc0 = 0.f, acc1 = 0.f;
    #pragma unroll 8
    for (int c = 0; c < HID / 4; ++c) {
        float4 a = xr0[c];
        float4 b = xr1[c];
        int k = c * 4;
        float w0 = w[j][k], w1 = w[j][k + 1], w2 = w[j][k + 2], w3 = w[j][k + 3];
        acc0 += a.x * w0 + a.y * w1 + a.z * w2 + a.w * w3;
        acc1 += b.x * w0 + b.y * w1 + b.z * w2 + b.w * w3;
    }
    P[(size_t)n0 * BOT + j] = acc0;
    if (v1) P[(size_t)(n0 + 1) * BOT + j] = acc1;
}

// out[n,k] = sum_j A2[n,j]*Wup[k,j] + b_up[k] + x[n,k]
__global__ __launch_bounds__(256) void k_out(
    const float* __restrict__ A2, const float* __restrict__ x,
    const float* __restrict__ Wup, const float* __restrict__ bup,
    float* __restrict__ out, int N, int npb)
{
    int k = threadIdx.x;
    float wreg[BOT];
    const float4* wr = (const float4*)(Wup + (size_t)k * BOT);
    #pragma unroll
    for (int c = 0; c < BOT / 4; ++c) {
        float4 v = wr[c];
        wreg[c * 4 + 0] = v.x; wreg[c * 4 + 1] = v.y;
        wreg[c * 4 + 2] = v.z; wreg[c * 4 + 3] = v.w;
    }
    float bk = bup[k];

    int n0 = blockIdx.x * npb;
    int n1 = n0 + npb;
    if (n1 > N) n1 = N;
    for (int n = n0; n < n1; ++n) {
        const float* av = A2 + (size_t)n * BOT;
        float s0 = 0.f, s1 = 0.f, s2 = 0.f, s3 = 0.f;
        #pragma unroll
        for (int j = 0; j < BOT; j += 4) {
            s0 += av[j + 0] * wreg[j + 0];
            s1 += av[j + 1] * wreg[j + 1];
            s2 += av[j + 2] * wreg[j + 2];
            s3 += av[j + 3] * wreg[j + 3];
        }
        float acc = bk + ((s0 + s1) + (s2 + s3));
        out[(size_t)n * HID + k] = acc + x[(size_t)n * HID + k];
    }
}

extern "C" void kernel_launch(void* const* d_in, const int* in_sizes, int n_in,
                              void* d_out, int out_size, void* d_ws, size_t ws_size,
                              hipStream_t stream) {
    const float* x  = (const float*)d_in[0];
    const int*   ei = (const int*)d_in[1];
    const float* Wd = (const float*)d_in[2];
    const float* bd = (const float*)d_in[3];
    const float* Wu = (const float*)d_in[4];
    const float* bu = (const float*)d_in[5];
    float* out = (float*)d_out;

    int N = in_sizes[0] / HID;   // 100000
    int E = in_sizes[1] / 2;     // 800000
    int NB32 = N * 32;           // gather threads

    char* ws = (char*)d_ws;
    int*   flags = (int*)ws;                                  // flags[1] = CSR cursor
    int*   deg   = (int*)(ws + 16);
    float* dinv  = (float*)(ws + 16 + (size_t)N * 4);
    int*   startp= (int*)(ws + 16 + (size_t)N * 8);
    int*   curp  = (int*)(ws + 16 + (size_t)N * 12);
    int2*  srcw  = (int2*)(ws + 16 + (size_t)N * 16);
    float* P     = (float*)(ws + 16 + (size_t)N * 16 + (size_t)E * 8);
    float* A1    = (float*)(ws + 16 + (size_t)N * 16 + (size_t)E * 8 + (size_t)N * 128);

    // zero flags + cursor + deg
    hipMemsetAsync(ws, 0, 16 + (size_t)N * 4, stream);
    k_detect<<<1, 64, 0, stream>>>(ei, flags);
    k_deg<<<(E + 255) / 256, 256, 0, stream>>>(ei, E, deg, flags);
    k_dinv<<<(N + 255) / 256, 256, 0, stream>>>(deg, dinv, N);

    // CSR build (destination-ordered)
    k_alloc<<<(N + 255) / 256, 256, 0, stream>>>(deg, startp, curp, flags + 1, N);
    k_fill<<<(E + 255) / 256, 256, 0, stream>>>(ei, E, dinv, curp, srcw, flags);

    // Layer 1: P = x @ Wd^T ; h1 = relu(gather(P) + bd)   (gather fuses self-loop)
    k_gemm_down<<<(((N + 1) / 2) * 32 + 255) / 256, 256, 0, stream>>>(x, Wd, P, N);
    k_gather<<<(NB32 + 255) / 256, 256, 0, stream>>>(P, dinv, startp, curp, srcw, bd, A1, N, 1);

    // Layer 2: A2 = gather(h1)   (A2 reuses P buffer)
    k_gather<<<(NB32 + 255) / 256, 256, 0, stream>>>(A1, dinv, startp, curp, srcw, bd, P, N, 0);

    // out = A2 @ Wu^T + bu + x
    int npb = (N + 2499) / 2500;
    k_out<<<(N + npb - 1) / npb, 256, 0, stream>>>(P, x, Wu, bu, out, N, npb);
}

// Round 5
// 447.590 us; speedup vs baseline: 3.0567x; 1.1544x over previous
//
#include <hip/hip_runtime.h>
#include <hip/hip_bf16.h>
#include <stdint.h>

#define HID 256
#define BOT 32

typedef short short8 __attribute__((ext_vector_type(8)));
typedef float floatx4 __attribute__((ext_vector_type(4)));

// fp32 -> bf16 raw bits (truncate; ~2^-8 rel err, irrelevant at 1e-5 weight scale)
__device__ __forceinline__ unsigned short f2bu(float f) {
    return (unsigned short)(__float_as_uint(f) >> 16);
}
__device__ __forceinline__ float bu2f(unsigned short u) {
    return __uint_as_float((unsigned int)u << 16);
}
// pack 8 consecutive fp32 (two float4) into a bf16 short8 fragment
__device__ __forceinline__ short8 pack8(float4 a, float4 b) {
    short8 r;
    r[0] = (short)f2bu(a.x); r[1] = (short)f2bu(a.y);
    r[2] = (short)f2bu(a.z); r[3] = (short)f2bu(a.w);
    r[4] = (short)f2bu(b.x); r[5] = (short)f2bu(b.y);
    r[6] = (short)f2bu(b.z); r[7] = (short)f2bu(b.w);
    return r;
}

// ---------------------------------------------------------------------------
// ws layout (N=100000, E=800000 -> ~27 MB):
//   [0)              int    flags[4]  (flags[0]: edge mode; flags[1]: CSR cursor)
//   [16)             int    deg[N]
//   [16+4N)          float  dinv[N]
//   [16+8N)          int    start[N]
//   [16+12N)         int    cur[N]
//   [16+16N)         int2   srcw[E]     (src, norm-weight bits)
//   [16+16N+8E)      ushort P[N*32]     (bf16; layer-1 proj, reused as A2)
//   [16+16N+8E+64N)  ushort A1[N*32]    (bf16; layer-1 aggregate -> h1)
// ---------------------------------------------------------------------------

// int64-vs-int32 edge_index: int64 values < 2^31 have all-zero high words.
__global__ void k_detect(const int* __restrict__ ei, int* __restrict__ flags) {
    int t = threadIdx.x;           // 64 threads
    int found = 0;
    for (int i = 0; i < 8; ++i) {
        int slot = 2 * (t * 8 + i) + 1;
        if (ei[slot] != 0) found = 1;
    }
    unsigned long long b = __ballot(found);
    if (t == 0) flags[0] = (b == 0ULL) ? 1 : 0;
}

__global__ void k_deg(const int* __restrict__ ei, int E, int* __restrict__ deg,
                      const int* __restrict__ flags) {
    int mode = flags[0];
    int e = blockIdx.x * blockDim.x + threadIdx.x;
    if (e >= E) return;
    int d = mode ? ei[2 * E + 2 * e] : ei[E + e];
    atomicAdd(deg + d, 1);
}

__global__ void k_dinv(const int* __restrict__ deg, float* __restrict__ dinv, int N) {
    int i = blockIdx.x * blockDim.x + threadIdx.x;
    if (i < N) dinv[i] = rsqrtf((float)(deg[i] + 1));  // +1 self-loop
}

// Per-node CSR region allocation: block scan + one global atomic per block.
__global__ __launch_bounds__(256) void k_alloc(const int* __restrict__ deg,
                                               int* __restrict__ start,
                                               int* __restrict__ cur,
                                               int* __restrict__ cursor, int N) {
    __shared__ int sdata[256];
    __shared__ int sbase;
    int tid = threadIdx.x;
    int i = blockIdx.x * 256 + tid;
    int d = (i < N) ? deg[i] : 0;
    sdata[tid] = d;
    __syncthreads();
    for (int off = 1; off < 256; off <<= 1) {
        int t = (tid >= off) ? sdata[tid - off] : 0;
        __syncthreads();
        sdata[tid] += t;
        __syncthreads();
    }
    if (tid == 0) sbase = atomicAdd(cursor, sdata[255]);
    __syncthreads();
    if (i < N) {
        int st = sbase + sdata[tid] - d;
        start[i] = st;
        cur[i] = st;
    }
}

__global__ void k_fill(const int* __restrict__ ei, int E,
                       const float* __restrict__ dinv,
                       int* __restrict__ cur, int2* __restrict__ srcw,
                       const int* __restrict__ flags) {
    int mode = flags[0];
    int e = blockIdx.x * blockDim.x + threadIdx.x;
    if (e >= E) return;
    int s, d;
    if (mode) { s = ei[2 * e]; d = ei[2 * E + 2 * e]; }
    else      { s = ei[e];     d = ei[E + e]; }
    float w = dinv[s] * dinv[d];
    int slot = atomicAdd(cur + d, 1);
    srcw[slot] = make_int2(s, __float_as_int(w));
}

// P[n,j] = sum_k x[n,k]*Wd[j,k] via mfma 16x16x32 bf16; P stored bf16.
// Wave per 16-node M-tile; Wd cached as 2 jtiles x 8 ksteps of B-frags.
__global__ __launch_bounds__(256) void k_gemm_down(
    const float* __restrict__ x, const float* __restrict__ Wd,
    unsigned short* __restrict__ P, int N, int nwaves)
{
    int wid  = (blockIdx.x * 256 + threadIdx.x) >> 6;
    int lane = threadIdx.x & 63;
    int m = lane & 15, q = lane >> 4;

    // B-frag: B[k][j'] = Wd[j0+j'][k]; lane j'=m holds k=ks*32+q*8..+7
    short8 bfr[2][8];
    #pragma unroll
    for (int jt = 0; jt < 2; ++jt) {
        const float4* wr = (const float4*)(Wd + (size_t)(jt * 16 + m) * HID);
        #pragma unroll
        for (int ks = 0; ks < 8; ++ks) {
            int c = (ks * 32 + q * 8) >> 2;
            bfr[jt][ks] = pack8(wr[c], wr[c + 1]);
        }
    }

    int tiles = (N + 15) >> 4;
    for (int t = wid; t < tiles; t += nwaves) {
        int n0 = t << 4;
        int row = n0 + m; if (row >= N) row = N - 1;
        const float4* xr = (const float4*)(x + (size_t)row * HID);
        floatx4 acc0 = {0.f, 0.f, 0.f, 0.f};
        floatx4 acc1 = {0.f, 0.f, 0.f, 0.f};
        #pragma unroll
        for (int ks = 0; ks < 8; ++ks) {
            int c = (ks * 32 + q * 8) >> 2;
            short8 af = pack8(xr[c], xr[c + 1]);   // A[m][k=ks*32+q*8+j]
            acc0 = __builtin_amdgcn_mfma_f32_16x16x32_bf16(af, bfr[0][ks], acc0, 0, 0, 0);
            acc1 = __builtin_amdgcn_mfma_f32_16x16x32_bf16(af, bfr[1][ks], acc1, 0, 0, 0);
        }
        #pragma unroll
        for (int r = 0; r < 4; ++r) {              // D: col=m, row=q*4+r
            int n = n0 + q * 4 + r;
            if (n < N) {
                P[(size_t)n * BOT + m]      = f2bu(acc0[r]);
                P[(size_t)n * BOT + 16 + m] = f2bu(acc1[r]);
            }
        }
    }
}

// Gather-aggregate over CSR (bf16 feature tables), fused self-loop/bias/relu.
__global__ __launch_bounds__(256) void k_gather(
    const unsigned short* __restrict__ feat, const float* __restrict__ dinv,
    const int* __restrict__ start, const int* __restrict__ endp,
    const int2* __restrict__ srcw, const float* __restrict__ bias,
    unsigned short* __restrict__ dst, int N, int relu_bias)
{
    int t = blockIdx.x * 256 + threadIdx.x;
    int n = t >> 5, j = t & 31;
    if (n >= N) return;
    float di = dinv[n];
    float acc = di * di * bu2f(feat[(size_t)n * BOT + j]);
    int k = start[n], en = endp[n];
    for (; k + 1 < en; k += 2) {       // unroll-2: overlap record + gather latency
        int2 p0 = srcw[k];
        int2 p1 = srcw[k + 1];
        acc += __int_as_float(p0.y) * bu2f(feat[(size_t)p0.x * BOT + j]);
        acc += __int_as_float(p1.y) * bu2f(feat[(size_t)p1.x * BOT + j]);
    }
    if (k < en) {
        int2 p = srcw[k];
        acc += __int_as_float(p.y) * bu2f(feat[(size_t)p.x * BOT + j]);
    }
    if (relu_bias) {
        acc += bias[j];
        acc = acc > 0.f ? acc : 0.f;
    }
    dst[(size_t)n * BOT + j] = f2bu(acc);
}

// out[n,f] = sum_j A2[n,j]*Wup[f,j] + bu[f] + x[n,f]; K=32 = one mfma per tile.
__global__ __launch_bounds__(256) void k_out(
    const unsigned short* __restrict__ A2, const float* __restrict__ x,
    const float* __restrict__ Wup, const float* __restrict__ bup,
    float* __restrict__ out, int N, int nwaves)
{
    int wid  = (blockIdx.x * 256 + threadIdx.x) >> 6;
    int lane = threadIdx.x & 63;
    int m = lane & 15, q = lane >> 4;

    // B-frags for 16 feature tiles: B[k=j][f] = Wup[f][j]; lane f'=m, k=q*8..+7
    short8 bfr[16];
    float  bv[16];
    #pragma unroll
    for (int ft = 0; ft < 16; ++ft) {
        const float4* wr = (const float4*)(Wup + (size_t)(ft * 16 + m) * BOT);
        bfr[ft] = pack8(wr[q * 2], wr[q * 2 + 1]);
        bv[ft]  = bup[ft * 16 + m];
    }

    int tiles = (N + 15) >> 4;
    for (int t = wid; t < tiles; t += nwaves) {
        int n0 = t << 4;
        int arow = n0 + m; if (arow >= N) arow = N - 1;
        short8 af = *(const short8*)(A2 + (size_t)arow * BOT + q * 8);
        #pragma unroll
        for (int ft = 0; ft < 16; ++ft) {
            floatx4 acc = {0.f, 0.f, 0.f, 0.f};
            acc = __builtin_amdgcn_mfma_f32_16x16x32_bf16(af, bfr[ft], acc, 0, 0, 0);
            int f = ft * 16 + m;
            #pragma unroll
            for (int r = 0; r < 4; ++r) {
                int n = n0 + q * 4 + r;
                if (n < N) {
                    size_t idx = (size_t)n * HID + f;
                    out[idx] = acc[r] + bv[ft] + x[idx];
                }
            }
        }
    }
}

extern "C" void kernel_launch(void* const* d_in, const int* in_sizes, int n_in,
                              void* d_out, int out_size, void* d_ws, size_t ws_size,
                              hipStream_t stream) {
    const float* x  = (const float*)d_in[0];
    const int*   ei = (const int*)d_in[1];
    const float* Wd = (const float*)d_in[2];
    const float* bd = (const float*)d_in[3];
    const float* Wu = (const float*)d_in[4];
    const float* bu = (const float*)d_in[5];
    float* out = (float*)d_out;

    int N = in_sizes[0] / HID;   // 100000
    int E = in_sizes[1] / 2;     // 800000
    int NB32 = N * 32;

    char* ws = (char*)d_ws;
    int*   flags = (int*)ws;                                  // flags[1] = CSR cursor
    int*   deg   = (int*)(ws + 16);
    float* dinv  = (float*)(ws + 16 + (size_t)N * 4);
    int*   startp= (int*)(ws + 16 + (size_t)N * 8);
    int*   curp  = (int*)(ws + 16 + (size_t)N * 12);
    int2*  srcw  = (int2*)(ws + 16 + (size_t)N * 16);
    unsigned short* P  = (unsigned short*)(ws + 16 + (size_t)N * 16 + (size_t)E * 8);
    unsigned short* A1 = (unsigned short*)(ws + 16 + (size_t)N * 16 + (size_t)E * 8 + (size_t)N * 64);

    hipMemsetAsync(ws, 0, 16 + (size_t)N * 4, stream);  // flags + cursor + deg
    k_detect<<<1, 64, 0, stream>>>(ei, flags);
    k_deg<<<(E + 255) / 256, 256, 0, stream>>>(ei, E, deg, flags);
    k_dinv<<<(N + 255) / 256, 256, 0, stream>>>(deg, dinv, N);

    // CSR build (destination-ordered)
    k_alloc<<<(N + 255) / 256, 256, 0, stream>>>(deg, startp, curp, flags + 1, N);
    k_fill<<<(E + 255) / 256, 256, 0, stream>>>(ei, E, dinv, curp, srcw, flags);

    // Layer 1: P = x @ Wd^T (MFMA) ; h1 = relu(gather(P) + bd)
    int gblocks = 1024;
    k_gemm_down<<<gblocks, 256, 0, stream>>>(x, Wd, P, N, gblocks * 4);
    k_gather<<<(NB32 + 255) / 256, 256, 0, stream>>>(P, dinv, startp, curp, srcw, bd, A1, N, 1);

    // Layer 2: A2 = gather(h1)  (reuses P buffer)
    k_gather<<<(NB32 + 255) / 256, 256, 0, stream>>>(A1, dinv, startp, curp, srcw, bd, P, N, 0);

    // out = A2 @ Wu^T + bu + x  (MFMA epilogue-fused)
    int oblocks = 1024;
    k_out<<<oblocks, 256, 0, stream>>>(P, x, Wu, bu, out, N, oblocks * 4);
}